// Round 1
// baseline (1826.695 us; speedup 1.0000x reference)
//
#include <hip/hip_runtime.h>
#include <hip/hip_bf16.h>

#define MAIN_BLOCK 128
#define MAIN_GRID 8192

__device__ __forceinline__ float wred32(float x) {
  #pragma unroll
  for (int m = 16; m >= 1; m >>= 1) x += __shfl_xor(x, m, 64);
  return x;
}
__device__ __forceinline__ float wred64(float x) {
  #pragma unroll
  for (int m = 32; m >= 1; m >>= 1) x += __shfl_xor(x, m, 64);
  return x;
}

__global__ void k_count(const int* __restrict__ dst, int E, int* __restrict__ deg) {
  for (int i = blockIdx.x * blockDim.x + threadIdx.x; i < E; i += gridDim.x * blockDim.x)
    atomicAdd(&deg[dst[i]], 1);
}

__global__ void k_scan1(const int* __restrict__ deg, int N, int* __restrict__ part,
                        int* __restrict__ bsum) {
  __shared__ int tmp[1024];
  int tid = threadIdx.x;
  int i = blockIdx.x * 1024 + tid;
  int v = (i < N) ? deg[i] : 0;
  tmp[tid] = v;
  __syncthreads();
  for (int ofs = 1; ofs < 1024; ofs <<= 1) {
    int t = (tid >= ofs) ? tmp[tid - ofs] : 0;
    __syncthreads();
    tmp[tid] += t;
    __syncthreads();
  }
  if (i < N) part[i] = tmp[tid] - v;      // exclusive within block
  if (tid == 1023) bsum[blockIdx.x] = tmp[tid];
}

__global__ void k_scan2(int* __restrict__ part, const int* __restrict__ bsum, int N,
                        int* __restrict__ cursor) {
  __shared__ int sbase;
  if (threadIdx.x == 0) {
    int b = 0;
    for (int j = 0; j < (int)blockIdx.x; j++) b += bsum[j];
    sbase = b;
  }
  __syncthreads();
  int i = blockIdx.x * 1024 + threadIdx.x;
  if (i < N) {
    int o = part[i] + sbase;
    part[i] = o;
    cursor[i] = o;
  }
}

__global__ void k_fill(const int* __restrict__ dst, int E, int* __restrict__ cursor,
                       int* __restrict__ csr) {
  for (int i = blockIdx.x * blockDim.x + threadIdx.x; i < E; i += gridDim.x * blockDim.x) {
    int d = dst[i];
    int slot = atomicAdd(&cursor[d], 1);
    csr[slot] = i;
  }
}

__launch_bounds__(MAIN_BLOCK)
__global__ void k_main(const float* __restrict__ x,
                       const int* __restrict__ esrc,
                       const float* __restrict__ edge_attr,
                       const float* __restrict__ W_msg,
                       const float* __restrict__ W_att,
                       const float* __restrict__ bias,
                       const float* __restrict__ gamma,
                       const float* __restrict__ beta,
                       const int* __restrict__ offsets,
                       const int* __restrict__ deg,
                       const int* __restrict__ csr,
                       float* __restrict__ out, int N) {
  __shared__ float s_watt[640];
  __shared__ alignas(16) float s_in[96];
  __shared__ float s_red[4];
  const int f = threadIdx.x;            // output feature, 0..127
  const int wv = f >> 6;                // wave id (0/1)
  const int l32 = f & 31;               // lane within 32-group
  const int h = f >> 5;                 // attention head for this feature

  // W_msg row f -> registers (96 VGPRs), loaded once per block from L2
  float w[96];
  #pragma unroll
  for (int k = 0; k < 96; k += 4) {
    float4 t = *(const float4*)&W_msg[f * 96 + k];
    w[k] = t.x; w[k + 1] = t.y; w[k + 2] = t.z; w[k + 3] = t.w;
  }
  for (int idx = f; idx < 640; idx += MAIN_BLOCK) s_watt[idx] = W_att[idx];
  const float bf = bias[f], gf = gamma[f], btf = beta[f];
  __syncthreads();

  for (int v = blockIdx.x; v < N; v += gridDim.x) {
    // pre_v[h] = W_att[h, 64:128] . x[v]  (each 32-group computes its head)
    float xva = x[v * 64 + l32];
    float xvb = x[v * 64 + 32 + l32];
    float pre = wred32(s_watt[h * 160 + 64 + l32] * xva +
                       s_watt[h * 160 + 96 + l32] * xvb);

    const int start = offsets[v];
    const int dg = deg[v];
    float acc = 0.f, ssum = 0.f;

    for (int j = 0; j < dg; j++) {
      const int eid = csr[start + j];
      const int u = esrc[eid];
      __syncthreads();                       // protect s_in from previous readers
      if (f < 64)       s_in[f] = x[u * 64 + f];
      else if (f < 96)  s_in[f] = edge_attr[eid * 32 + (f - 64)];
      __syncthreads();

      // attention logit for head h (butterfly leaves sum in all 32 lanes)
      float p = s_watt[h * 160 + l32]        * s_in[l32] +
                s_watt[h * 160 + 32 + l32]   * s_in[32 + l32] +
                s_watt[h * 160 + 128 + l32]  * s_in[64 + l32];
      p = wred32(p) + pre;
      p = (p > 0.f) ? p : 0.2f * p;          // leaky relu
      const float att = __expf(p);           // no max-subtraction needed (fp32)

      // message feature f = W_msg[f,:] . [x_u ; e_attr]
      float m0 = 0.f, m1 = 0.f, m2 = 0.f, m3 = 0.f;
      #pragma unroll
      for (int k = 0; k < 96; k += 4) {
        float4 t = *(const float4*)&s_in[k]; // uniform-address LDS b128 (broadcast)
        m0 = fmaf(w[k],     t.x, m0);
        m1 = fmaf(w[k + 1], t.y, m1);
        m2 = fmaf(w[k + 2], t.z, m2);
        m3 = fmaf(w[k + 3], t.w, m3);
      }
      const float m = (m0 + m1) + (m2 + m3);
      acc = fmaf(att, m, acc);
      ssum += att;
    }

    // softmax-normalize + bias, then LayerNorm over 128 features (2 waves)
    const float o = acc / (ssum + 1e-9f) + bf;
    float s1 = wred64(o);
    if ((f & 63) == 0) s_red[wv] = s1;
    __syncthreads();
    const float mean = (s_red[0] + s_red[1]) * (1.0f / 128.0f);
    const float dlt = o - mean;
    float s2 = wred64(dlt * dlt);
    if ((f & 63) == 0) s_red[2 + wv] = s2;
    __syncthreads();
    const float var = (s_red[2] + s_red[3]) * (1.0f / 128.0f);
    out[v * 128 + f] = dlt * rsqrtf(var + 1e-5f) * gf + btf;
    __syncthreads();                          // protect s_red before next node
  }
}

extern "C" void kernel_launch(void* const* d_in, const int* in_sizes, int n_in,
                              void* d_out, int out_size, void* d_ws, size_t ws_size,
                              hipStream_t stream) {
  const float* x     = (const float*)d_in[0];
  const int*   ei    = (const int*)d_in[1];
  const float* ea    = (const float*)d_in[2];
  const float* W_msg = (const float*)d_in[3];
  const float* W_att = (const float*)d_in[4];
  const float* bias  = (const float*)d_in[5];
  const float* gamma = (const float*)d_in[6];
  const float* beta  = (const float*)d_in[7];
  float* out = (float*)d_out;

  const int N = in_sizes[0] / 64;
  const int E = in_sizes[1] / 2;
  const int* esrc = ei;
  const int* edst = ei + E;

  int* deg     = (int*)d_ws;
  int* offsets = deg + N;
  int* cursor  = offsets + N;
  int* bsum    = cursor + N;
  int* csr     = bsum + 2048;

  hipMemsetAsync(deg, 0, (size_t)N * sizeof(int), stream);
  const int SB = (N + 1023) / 1024;

  k_count<<<2048, 256, 0, stream>>>(edst, E, deg);
  k_scan1<<<SB, 1024, 0, stream>>>(deg, N, offsets, bsum);
  k_scan2<<<SB, 1024, 0, stream>>>(offsets, bsum, N, cursor);
  k_fill<<<2048, 256, 0, stream>>>(edst, E, cursor, csr);
  k_main<<<MAIN_GRID, MAIN_BLOCK, 0, stream>>>(x, esrc, ea, W_msg, W_att, bias,
                                               gamma, beta, offsets, deg, csr, out, N);
}

// Round 2
// 1513.698 us; speedup vs baseline: 1.2068x; 1.2068x over previous
//
#include <hip/hip_runtime.h>
#include <hip/hip_bf16.h>

#define MAIN_BLOCK 128
#define MAIN_GRID 8192
#define EPG 8

__device__ __forceinline__ float wred32(float x) {
  #pragma unroll
  for (int m = 16; m >= 1; m >>= 1) x += __shfl_xor(x, m, 64);
  return x;
}
__device__ __forceinline__ float wred64(float x) {
  #pragma unroll
  for (int m = 32; m >= 1; m >>= 1) x += __shfl_xor(x, m, 64);
  return x;
}

__global__ void k_count(const int* __restrict__ dst, int E, int* __restrict__ deg) {
  for (int i = blockIdx.x * blockDim.x + threadIdx.x; i < E; i += gridDim.x * blockDim.x)
    atomicAdd(&deg[dst[i]], 1);
}

__global__ void k_scan1(const int* __restrict__ deg, int N, int* __restrict__ part,
                        int* __restrict__ bsum) {
  __shared__ int tmp[1024];
  int tid = threadIdx.x;
  int i = blockIdx.x * 1024 + tid;
  int v = (i < N) ? deg[i] : 0;
  tmp[tid] = v;
  __syncthreads();
  for (int ofs = 1; ofs < 1024; ofs <<= 1) {
    int t = (tid >= ofs) ? tmp[tid - ofs] : 0;
    __syncthreads();
    tmp[tid] += t;
    __syncthreads();
  }
  if (i < N) part[i] = tmp[tid] - v;
  if (tid == 1023) bsum[blockIdx.x] = tmp[tid];
}

__global__ void k_scan2(int* __restrict__ part, const int* __restrict__ bsum, int N,
                        int* __restrict__ cursor) {
  __shared__ int sbase;
  if (threadIdx.x == 0) {
    int b = 0;
    for (int j = 0; j < (int)blockIdx.x; j++) b += bsum[j];
    sbase = b;
  }
  __syncthreads();
  int i = blockIdx.x * 1024 + threadIdx.x;
  if (i < N) {
    int o = part[i] + sbase;
    part[i] = o;
    cursor[i] = o;
  }
}

__global__ void k_fill(const int* __restrict__ src, const int* __restrict__ dst, int E,
                       int* __restrict__ cursor, int2* __restrict__ csr2) {
  for (int i = blockIdx.x * blockDim.x + threadIdx.x; i < E; i += gridDim.x * blockDim.x) {
    int d = dst[i];
    int slot = atomicAdd(&cursor[d], 1);
    csr2[slot] = make_int2(src[i], i);   // (src node, edge id)
  }
}

__launch_bounds__(MAIN_BLOCK)
__global__ void k_main(const float* __restrict__ x,
                       const float* __restrict__ edge_attr,
                       const float* __restrict__ W_msg,
                       const float* __restrict__ W_att,
                       const float* __restrict__ bias,
                       const float* __restrict__ gamma,
                       const float* __restrict__ beta,
                       const int* __restrict__ offsets,
                       const int* __restrict__ deg,
                       const int2* __restrict__ csr2,
                       float* __restrict__ out, int N) {
  __shared__ float s_in[2][EPG][96];     // [buf][edge][x(64);ea(32)]
  __shared__ float s_red[4];
  const int f = threadIdx.x;             // output feature 0..127
  const int wv = f >> 6;
  const int l32 = f & 31;
  const int h = f >> 5;                  // attention head
  const int exj = f >> 6;                // base edge for x slots (0/1)
  const int cx  = f & 63;
  const int eej = f >> 5;                // base edge for ea slots (0..3)
  const int cea = f & 31;

  // W_msg row f resident in 24 float4 registers
  float4 w4[24];
  #pragma unroll
  for (int k = 0; k < 24; k++) w4[k] = ((const float4*)W_msg)[f * 24 + k];

  // W_att coefficients for head h, hoisted to registers
  const float wa_xs0 = W_att[h * 160 + l32];
  const float wa_xs1 = W_att[h * 160 + 32 + l32];
  const float wa_xd0 = W_att[h * 160 + 64 + l32];
  const float wa_xd1 = W_att[h * 160 + 96 + l32];
  const float wa_ea  = W_att[h * 160 + 128 + l32];
  const float bf = bias[f], gf = gamma[f], btf = beta[f];

  float rx[4], rea[2];

  for (int v = blockIdx.x; v < N; v += gridDim.x) {
    const float pre = wred32(wa_xd0 * x[v * 64 + l32] + wa_xd1 * x[v * 64 + 32 + l32]);
    const int start = offsets[v];
    const int dg = deg[v];
    float acc = 0.f, ssum = 0.f;

    if (dg > 0) {
      const int ngroups = (dg + EPG - 1) / EPG;
      // prefetch group 0 into registers
      {
        const int rem = min(EPG, dg);
        #pragma unroll
        for (int j = 0; j < 4; j++) {
          int2 id = csr2[start + min(exj + 2 * j, rem - 1)];
          rx[j] = x[id.x * 64 + cx];
        }
        #pragma unroll
        for (int j = 0; j < 2; j++) {
          int2 id = csr2[start + min(eej + 4 * j, rem - 1)];
          rea[j] = edge_attr[id.y * 32 + cea];
        }
      }
      int b = 0;
      for (int g = 0; g < ngroups; g++) {
        // (A) commit prefetched regs to LDS buffer b
        #pragma unroll
        for (int j = 0; j < 4; j++) s_in[b][exj + 2 * j][cx] = rx[j];
        #pragma unroll
        for (int j = 0; j < 2; j++) s_in[b][eej + 4 * j][64 + cea] = rea[j];
        __syncthreads();
        // (C) issue gathers for group g+1 (hidden under compute below)
        if (g + 1 < ngroups) {
          const int gb = (g + 1) * EPG;
          const int nrem = min(EPG, dg - gb);
          #pragma unroll
          for (int j = 0; j < 4; j++) {
            int2 id = csr2[start + gb + min(exj + 2 * j, nrem - 1)];
            rx[j] = x[id.x * 64 + cx];
          }
          #pragma unroll
          for (int j = 0; j < 2; j++) {
            int2 id = csr2[start + gb + min(eej + 4 * j, nrem - 1)];
            rea[j] = edge_attr[id.y * 32 + cea];
          }
        }
        // (D) compute 8 (or rem) edges from buffer b
        const int rem = min(EPG, dg - g * EPG);
        for (int j = 0; j < rem; j++) {
          const float* sp = s_in[b][j];
          float p = wa_xs0 * sp[l32] + wa_xs1 * sp[32 + l32] + wa_ea * sp[64 + l32];
          p = wred32(p) + pre;
          p = (p > 0.f) ? p : 0.2f * p;
          const float att = __expf(p);
          const float4* s4 = (const float4*)sp;
          float m0 = 0.f, m1 = 0.f, m2 = 0.f, m3 = 0.f;
          #pragma unroll
          for (int k = 0; k < 24; k++) {
            float4 t = s4[k];
            m0 = fmaf(w4[k].x, t.x, m0);
            m1 = fmaf(w4[k].y, t.y, m1);
            m2 = fmaf(w4[k].z, t.z, m2);
            m3 = fmaf(w4[k].w, t.w, m3);
          }
          acc = fmaf(att, (m0 + m1) + (m2 + m3), acc);
          ssum += att;
        }
        b ^= 1;
      }
    }

    // softmax-normalize + bias, then LayerNorm over 128 features
    const float o = acc / (ssum + 1e-9f) + bf;
    float s1 = wred64(o);
    if ((f & 63) == 0) s_red[wv] = s1;
    __syncthreads();
    const float mean = (s_red[0] + s_red[1]) * (1.0f / 128.0f);
    const float dlt = o - mean;
    float s2 = wred64(dlt * dlt);
    if ((f & 63) == 0) s_red[2 + wv] = s2;
    __syncthreads();
    const float var = (s_red[2] + s_red[3]) * (1.0f / 128.0f);
    out[v * 128 + f] = dlt * rsqrtf(var + 1e-5f) * gf + btf;
    __syncthreads();
  }
}

extern "C" void kernel_launch(void* const* d_in, const int* in_sizes, int n_in,
                              void* d_out, int out_size, void* d_ws, size_t ws_size,
                              hipStream_t stream) {
  const float* x     = (const float*)d_in[0];
  const int*   ei    = (const int*)d_in[1];
  const float* ea    = (const float*)d_in[2];
  const float* W_msg = (const float*)d_in[3];
  const float* W_att = (const float*)d_in[4];
  const float* bias  = (const float*)d_in[5];
  const float* gamma = (const float*)d_in[6];
  const float* beta  = (const float*)d_in[7];
  float* out = (float*)d_out;

  const int N = in_sizes[0] / 64;
  const int E = in_sizes[1] / 2;
  const int* esrc = ei;
  const int* edst = ei + E;

  int* deg     = (int*)d_ws;
  int* offsets = deg + N;
  int* cursor  = offsets + N;
  int* bsum    = cursor + N;
  int2* csr2   = (int2*)(bsum + 2048);

  hipMemsetAsync(deg, 0, (size_t)N * sizeof(int), stream);
  const int SB = (N + 1023) / 1024;

  k_count<<<2048, 256, 0, stream>>>(edst, E, deg);
  k_scan1<<<SB, 1024, 0, stream>>>(deg, N, offsets, bsum);
  k_scan2<<<SB, 1024, 0, stream>>>(offsets, bsum, N, cursor);
  k_fill<<<2048, 256, 0, stream>>>(esrc, edst, E, cursor, csr2);
  k_main<<<MAIN_GRID, MAIN_BLOCK, 0, stream>>>(x, ea, W_msg, W_att, bias,
                                               gamma, beta, offsets, deg, csr2, out, N);
}

// Round 3
// 833.650 us; speedup vs baseline: 2.1912x; 1.8157x over previous
//
#include <hip/hip_runtime.h>
#include <hip/hip_bf16.h>

#define MAIN_BLOCK 128
#define MAIN_GRID 8192
#define EPG 16

typedef __attribute__((ext_vector_type(8))) short short8;
typedef __attribute__((ext_vector_type(4))) float f32x4;

__device__ __forceinline__ unsigned short fbf(float f) {
  union { float f; unsigned u; } v; v.f = f;
  unsigned r = v.u + 0x7fffu + ((v.u >> 16) & 1u);   // RNE
  return (unsigned short)(r >> 16);
}
__device__ __forceinline__ unsigned pk2(float a, float b) {
  return (unsigned)fbf(a) | ((unsigned)fbf(b) << 16);
}

__device__ __forceinline__ float wred32(float x) {
  #pragma unroll
  for (int m = 16; m >= 1; m >>= 1) x += __shfl_xor(x, m, 64);
  return x;
}
__device__ __forceinline__ float wred64(float x) {
  #pragma unroll
  for (int m = 32; m >= 1; m >>= 1) x += __shfl_xor(x, m, 64);
  return x;
}

__global__ void k_count(const int* __restrict__ dst, int E, int* __restrict__ deg) {
  for (int i = blockIdx.x * blockDim.x + threadIdx.x; i < E; i += gridDim.x * blockDim.x)
    atomicAdd(&deg[dst[i]], 1);
}

__global__ void k_scan1(const int* __restrict__ deg, int N, int* __restrict__ part,
                        int* __restrict__ bsum) {
  __shared__ int tmp[1024];
  int tid = threadIdx.x;
  int i = blockIdx.x * 1024 + tid;
  int v = (i < N) ? deg[i] : 0;
  tmp[tid] = v;
  __syncthreads();
  for (int ofs = 1; ofs < 1024; ofs <<= 1) {
    int t = (tid >= ofs) ? tmp[tid - ofs] : 0;
    __syncthreads();
    tmp[tid] += t;
    __syncthreads();
  }
  if (i < N) part[i] = tmp[tid] - v;
  if (tid == 1023) bsum[blockIdx.x] = tmp[tid];
}

__global__ void k_scan2(int* __restrict__ part, const int* __restrict__ bsum, int N,
                        int* __restrict__ cursor) {
  __shared__ int sbase;
  if (threadIdx.x == 0) {
    int b = 0;
    for (int j = 0; j < (int)blockIdx.x; j++) b += bsum[j];
    sbase = b;
  }
  __syncthreads();
  int i = blockIdx.x * 1024 + threadIdx.x;
  if (i < N) {
    int o = part[i] + sbase;
    part[i] = o;
    cursor[i] = o;
  }
}

__global__ void k_fill(const int* __restrict__ src, const int* __restrict__ dst, int E,
                       int* __restrict__ cursor, int2* __restrict__ csr2) {
  for (int i = blockIdx.x * blockDim.x + threadIdx.x; i < E; i += gridDim.x * blockDim.x) {
    int d = dst[i];
    int slot = atomicAdd(&cursor[d], 1);
    csr2[slot] = make_int2(src[i], i);
  }
}

__global__ void k_main(const float* __restrict__ x,
                       const float* __restrict__ edge_attr,
                       const float* __restrict__ W_msg,
                       const float* __restrict__ W_att,
                       const float* __restrict__ bias,
                       const float* __restrict__ gamma,
                       const float* __restrict__ beta,
                       const int* __restrict__ offsets,
                       const int* __restrict__ deg,
                       const int2* __restrict__ csr2,
                       float* __restrict__ out, int N) {
  // A tile: 16 edges x 96 k (bf16), row stride 208 B (13x16B -> 2-way/8-access
  // bank pattern on both b128 writes and fragment reads = conflict-free)
  __shared__ __align__(16) unsigned char s_A[2][16 * 208];
  __shared__ float s_att[2][16][4];     // per-wave att table [row][head]
  __shared__ float s_pre[16];           // pre[h] (4 used, padded for col reads)
  __shared__ float s_ssum[4];
  __shared__ float s_red[4];

  const int f   = threadIdx.x;
  const int w   = f >> 6;               // wave 0/1 -> features w*64..w*64+63
  const int l   = f & 63;
  const int col = l & 15;               // MFMA A-row / C-col
  const int kq  = l >> 4;               // k-quarter 0..3 (also C row-group)
  const int l32 = f & 31;
  const int h   = f >> 5;
  const int e16 = f >> 3;               // staging edge slot 0..15
  const int c8  = f & 7;                // staging chunk

  if (f < 16) s_pre[f] = 0.f;

  // W_msg B-fragments: lane holds W_msg[w*64+t*16+col][kk*32+kq*8 .. +7] as bf16
  short8 wmsg[4][3];
  #pragma unroll
  for (int t = 0; t < 4; t++) {
    const float* wp = &W_msg[(w * 64 + t * 16 + col) * 96];
    #pragma unroll
    for (int kk = 0; kk < 3; kk++) {
      const float* p = wp + kk * 32 + kq * 8;
      short8 s;
      #pragma unroll
      for (int i = 0; i < 8; i++) s[i] = (short)fbf(p[i]);
      wmsg[t][kk] = s;
    }
  }
  // W_att B-fragments (cols 0..3 = heads, rest zero); k<64 -> xs, k>=64 -> ea(+64)
  short8 watt[3];
  #pragma unroll
  for (int kk = 0; kk < 3; kk++) {
    short8 s = {0, 0, 0, 0, 0, 0, 0, 0};
    if (col < 4) {
      #pragma unroll
      for (int i = 0; i < 8; i++) {
        int k = kk * 32 + kq * 8 + i;
        int idx = (k < 64) ? k : (64 + k);
        s[i] = (short)fbf(W_att[col * 160 + idx]);
      }
    }
    watt[kk] = s;
  }
  const float wa_xd0 = W_att[h * 160 + 64 + l32];
  const float wa_xd1 = W_att[h * 160 + 96 + l32];
  float biasr[4], gr[4], br[4];
  #pragma unroll
  for (int t = 0; t < 4; t++) {
    int ft = w * 64 + t * 16 + col;
    biasr[t] = bias[ft]; gr[t] = gamma[ft]; br[t] = beta[ft];
  }

  for (int v = blockIdx.x; v < N; v += gridDim.x) {
    float pv = wred32(wa_xd0 * x[v * 64 + l32] + wa_xd1 * x[v * 64 + 32 + l32]);
    if (l32 == 0) s_pre[h] = pv;

    const int start = offsets[v];
    const int dg = deg[v];
    float acc[4][4] = {};
    float g_ssum = 0.f;

    if (dg > 0) {
      const int ng = (dg + EPG - 1) / EPG;
      int2 id; float4 rxa, rxb, rec;
      {
        const int rem = min(EPG, dg);
        id = csr2[start + min(e16, rem - 1)];
        const float4* xp = (const float4*)&x[(size_t)id.x * 64 + c8 * 8];
        rxa = xp[0]; rxb = xp[1];
        rec = *(const float4*)&edge_attr[(size_t)id.y * 32 + c8 * 4];
      }
      int b = 0;
      for (int g = 0; g < ng; g++) {
        // commit prefetched regs to LDS tile b (bf16)
        unsigned char* base = &s_A[b][e16 * 208];
        uint4 px;
        px.x = pk2(rxa.x, rxa.y); px.y = pk2(rxa.z, rxa.w);
        px.z = pk2(rxb.x, rxb.y); px.w = pk2(rxb.z, rxb.w);
        *(uint4*)(base + c8 * 16) = px;
        uint2 pe; pe.x = pk2(rec.x, rec.y); pe.y = pk2(rec.z, rec.w);
        *(uint2*)(base + 128 + c8 * 8) = pe;
        __syncthreads();
        // prefetch next group (hides gather latency under MFMAs)
        if (g + 1 < ng) {
          const int gb = (g + 1) * EPG;
          const int rem = min(EPG, dg - gb);
          id = csr2[start + gb + min(e16, rem - 1)];
          const float4* xp = (const float4*)&x[(size_t)id.x * 64 + c8 * 8];
          rxa = xp[0]; rxb = xp[1];
          rec = *(const float4*)&edge_attr[(size_t)id.y * 32 + c8 * 4];
        }
        // A fragments (shared by logit + message MFMAs)
        const unsigned char* arow = &s_A[b][(l & 15) * 208];
        short8 a0 = *(const short8*)(arow + 0 * 64 + kq * 16);
        short8 a1 = *(const short8*)(arow + 1 * 64 + kq * 16);
        short8 a2 = *(const short8*)(arow + 2 * 64 + kq * 16);
        // attention logits (16 edges x 4 heads)
        f32x4 cl = {0.f, 0.f, 0.f, 0.f};
        cl = __builtin_amdgcn_mfma_f32_16x16x32_bf16(a0, watt[0], cl, 0, 0, 0);
        cl = __builtin_amdgcn_mfma_f32_16x16x32_bf16(a1, watt[1], cl, 0, 0, 0);
        cl = __builtin_amdgcn_mfma_f32_16x16x32_bf16(a2, watt[2], cl, 0, 0, 0);
        // messages (16 edges x 64 features per wave)
        f32x4 cm0 = {0.f,0.f,0.f,0.f}, cm1 = {0.f,0.f,0.f,0.f};
        f32x4 cm2 = {0.f,0.f,0.f,0.f}, cm3 = {0.f,0.f,0.f,0.f};
        cm0 = __builtin_amdgcn_mfma_f32_16x16x32_bf16(a0, wmsg[0][0], cm0, 0, 0, 0);
        cm0 = __builtin_amdgcn_mfma_f32_16x16x32_bf16(a1, wmsg[0][1], cm0, 0, 0, 0);
        cm0 = __builtin_amdgcn_mfma_f32_16x16x32_bf16(a2, wmsg[0][2], cm0, 0, 0, 0);
        cm1 = __builtin_amdgcn_mfma_f32_16x16x32_bf16(a0, wmsg[1][0], cm1, 0, 0, 0);
        cm1 = __builtin_amdgcn_mfma_f32_16x16x32_bf16(a1, wmsg[1][1], cm1, 0, 0, 0);
        cm1 = __builtin_amdgcn_mfma_f32_16x16x32_bf16(a2, wmsg[1][2], cm1, 0, 0, 0);
        cm2 = __builtin_amdgcn_mfma_f32_16x16x32_bf16(a0, wmsg[2][0], cm2, 0, 0, 0);
        cm2 = __builtin_amdgcn_mfma_f32_16x16x32_bf16(a1, wmsg[2][1], cm2, 0, 0, 0);
        cm2 = __builtin_amdgcn_mfma_f32_16x16x32_bf16(a2, wmsg[2][2], cm2, 0, 0, 0);
        cm3 = __builtin_amdgcn_mfma_f32_16x16x32_bf16(a0, wmsg[3][0], cm3, 0, 0, 0);
        cm3 = __builtin_amdgcn_mfma_f32_16x16x32_bf16(a1, wmsg[3][1], cm3, 0, 0, 0);
        cm3 = __builtin_amdgcn_mfma_f32_16x16x32_bf16(a2, wmsg[3][2], cm3, 0, 0, 0);
        // att epilogue: leaky-relu + exp, masked past degree
        const float prec = s_pre[col];
        const int gb0 = g * EPG;
        float attv[4];
        #pragma unroll
        for (int r = 0; r < 4; r++) {
          float lg = cl[r] + prec;
          lg = (lg > 0.f) ? lg : 0.2f * lg;
          int row = gb0 + kq * 4 + r;
          attv[r] = (row < dg) ? __expf(lg) : 0.f;
        }
        g_ssum += (attv[0] + attv[1]) + (attv[2] + attv[3]);
        if (col < 4) {
          #pragma unroll
          for (int r = 0; r < 4; r++) s_att[w][kq * 4 + r][col] = attv[r];
        }
        float av0[4], av1[4];
        #pragma unroll
        for (int r = 0; r < 4; r++) {
          av0[r] = s_att[w][kq * 4 + r][w * 2 + 0];
          av1[r] = s_att[w][kq * 4 + r][w * 2 + 1];
        }
        #pragma unroll
        for (int r = 0; r < 4; r++) {
          acc[0][r] = fmaf(av0[r], cm0[r], acc[0][r]);
          acc[1][r] = fmaf(av0[r], cm1[r], acc[1][r]);
          acc[2][r] = fmaf(av1[r], cm2[r], acc[2][r]);
          acc[3][r] = fmaf(av1[r], cm3[r], acc[3][r]);
        }
        b ^= 1;
      }
    }

    // softmax denom, normalize, bias, LayerNorm (features replicated x4 over kq)
    g_ssum += __shfl_xor(g_ssum, 16, 64);
    g_ssum += __shfl_xor(g_ssum, 32, 64);
    if (f < 4) s_ssum[f] = g_ssum;
    __syncthreads();
    const float inv0 = 1.f / (s_ssum[w * 2 + 0] + 1e-9f);
    const float inv1 = 1.f / (s_ssum[w * 2 + 1] + 1e-9f);
    float o[4];
    #pragma unroll
    for (int t = 0; t < 4; t++) {
      float s = (acc[t][0] + acc[t][1]) + (acc[t][2] + acc[t][3]);
      s += __shfl_xor(s, 16, 64);
      s += __shfl_xor(s, 32, 64);
      o[t] = s * ((t < 2) ? inv0 : inv1) + biasr[t];
    }
    float s1 = wred64((o[0] + o[1]) + (o[2] + o[3]));
    if (l == 0) s_red[w] = s1;
    __syncthreads();
    const float mean = (s_red[0] + s_red[1]) * (1.f / 512.f);
    const float d0 = o[0] - mean, d1 = o[1] - mean, d2 = o[2] - mean, d3 = o[3] - mean;
    float s2 = wred64(d0 * d0 + d1 * d1 + d2 * d2 + d3 * d3);
    if (l == 0) s_red[2 + w] = s2;
    __syncthreads();
    const float var = (s_red[2] + s_red[3]) * (1.f / 512.f);
    const float rstd = rsqrtf(var + 1e-5f);
    if (kq == 0) {
      out[v * 128 + w * 64 + 0 + col]  = d0 * rstd * gr[0] + br[0];
      out[v * 128 + w * 64 + 16 + col] = d1 * rstd * gr[1] + br[1];
      out[v * 128 + w * 64 + 32 + col] = d2 * rstd * gr[2] + br[2];
      out[v * 128 + w * 64 + 48 + col] = d3 * rstd * gr[3] + br[3];
    }
    __syncthreads();
  }
}

extern "C" void kernel_launch(void* const* d_in, const int* in_sizes, int n_in,
                              void* d_out, int out_size, void* d_ws, size_t ws_size,
                              hipStream_t stream) {
  const float* x     = (const float*)d_in[0];
  const int*   ei    = (const int*)d_in[1];
  const float* ea    = (const float*)d_in[2];
  const float* W_msg = (const float*)d_in[3];
  const float* W_att = (const float*)d_in[4];
  const float* bias  = (const float*)d_in[5];
  const float* gamma = (const float*)d_in[6];
  const float* beta  = (const float*)d_in[7];
  float* out = (float*)d_out;

  const int N = in_sizes[0] / 64;
  const int E = in_sizes[1] / 2;
  const int* esrc = ei;
  const int* edst = ei + E;

  int* deg     = (int*)d_ws;
  int* offsets = deg + N;
  int* cursor  = offsets + N;
  int* bsum    = cursor + N;
  int2* csr2   = (int2*)(bsum + 2048);

  hipMemsetAsync(deg, 0, (size_t)N * sizeof(int), stream);
  const int SB = (N + 1023) / 1024;

  k_count<<<2048, 256, 0, stream>>>(edst, E, deg);
  k_scan1<<<SB, 1024, 0, stream>>>(deg, N, offsets, bsum);
  k_scan2<<<SB, 1024, 0, stream>>>(offsets, bsum, N, cursor);
  k_fill<<<2048, 256, 0, stream>>>(esrc, edst, E, cursor, csr2);
  k_main<<<MAIN_GRID, MAIN_BLOCK, 0, stream>>>(x, ea, W_msg, W_att, bias,
                                               gamma, beta, offsets, deg, csr2, out, N);
}

// Round 4
// 518.211 us; speedup vs baseline: 3.5250x; 1.6087x over previous
//
#include <hip/hip_runtime.h>
#include <hip/hip_bf16.h>

typedef __attribute__((ext_vector_type(8))) short short8;
typedef __attribute__((ext_vector_type(4))) float f32x4;

__device__ __forceinline__ unsigned short fbf(float f) {
  union { float f; unsigned u; } v; v.f = f;
  unsigned r = v.u + 0x7fffu + ((v.u >> 16) & 1u);   // RNE
  return (unsigned short)(r >> 16);
}
__device__ __forceinline__ unsigned pk2(float a, float b) {
  return (unsigned)fbf(a) | ((unsigned)fbf(b) << 16);
}
__device__ __forceinline__ float ubf(unsigned hi) {   // bf16 bits (in low16) -> float
  union { unsigned u; float f; } v; v.u = hi << 16; return v.f;
}
__device__ __forceinline__ float dot4(float4 a, float4 b) {
  return fmaf(a.x, b.x, fmaf(a.y, b.y, fmaf(a.z, b.z, a.w * b.w)));
}

// ---------------- CSR build ----------------
__global__ void k_count(const int* __restrict__ dst, int E, int* __restrict__ deg) {
  for (int i = blockIdx.x * blockDim.x + threadIdx.x; i < E; i += gridDim.x * blockDim.x)
    atomicAdd(&deg[dst[i]], 1);
}

__global__ void k_scan1(const int* __restrict__ deg, int N, int* __restrict__ part,
                        int* __restrict__ bsum) {
  __shared__ int tmp[1024];
  int tid = threadIdx.x;
  int i = blockIdx.x * 1024 + tid;
  int v = (i < N) ? deg[i] : 0;
  tmp[tid] = v;
  __syncthreads();
  for (int ofs = 1; ofs < 1024; ofs <<= 1) {
    int t = (tid >= ofs) ? tmp[tid - ofs] : 0;
    __syncthreads();
    tmp[tid] += t;
    __syncthreads();
  }
  if (i < N) part[i] = tmp[tid] - v;
  if (tid == 1023) bsum[blockIdx.x] = tmp[tid];
}

__global__ void k_scan2(int* __restrict__ part, const int* __restrict__ bsum, int N,
                        int* __restrict__ cursor) {
  __shared__ int sbase;
  if (threadIdx.x == 0) {
    int b = 0;
    for (int j = 0; j < (int)blockIdx.x; j++) b += bsum[j];
    sbase = b;
  }
  __syncthreads();
  int i = blockIdx.x * 1024 + threadIdx.x;
  if (i < N) {
    int o = part[i] + sbase;
    part[i] = o;
    cursor[i] = o;
  }
}

__global__ void k_fill(const int* __restrict__ src, const int* __restrict__ dst, int E,
                       int* __restrict__ cursor, int2* __restrict__ csr2) {
  for (int i = blockIdx.x * blockDim.x + threadIdx.x; i < E; i += gridDim.x * blockDim.x) {
    int d = dst[i];
    int slot = atomicAdd(&cursor[d], 1);
    csr2[slot] = make_int2(src[i], i);
  }
}

// ---------------- A_s / A_d tables ----------------
__launch_bounds__(256)
__global__ void k_pre(const float* __restrict__ x, const float* __restrict__ W_att,
                      float4* __restrict__ A_s, float4* __restrict__ A_d, int N) {
  __shared__ float4 s_wa[160];                 // 4 heads x 40 float4 (row len 160)
  if (threadIdx.x < 160) s_wa[threadIdx.x] = ((const float4*)W_att)[threadIdx.x];
  __syncthreads();
  for (int v = blockIdx.x * blockDim.x + threadIdx.x; v < N; v += gridDim.x * blockDim.x) {
    const float4* xp = (const float4*)&x[v * 64];
    float4 xq[16];
    #pragma unroll
    for (int k = 0; k < 16; k++) xq[k] = xp[k];
    float as[4] = {}, ad[4] = {};
    #pragma unroll
    for (int h = 0; h < 4; h++) {
      #pragma unroll
      for (int k = 0; k < 16; k++) {
        as[h] += dot4(s_wa[h * 40 + k], xq[k]);
        ad[h] += dot4(s_wa[h * 40 + 16 + k], xq[k]);
      }
    }
    A_s[v] = make_float4(as[0], as[1], as[2], as[3]);
    A_d[v] = make_float4(ad[0], ad[1], ad[2], ad[3]);
  }
}

// ---------------- per-edge attention weights ----------------
__launch_bounds__(256)
__global__ void k_att(const float* __restrict__ ea, const int* __restrict__ esrc,
                      const int* __restrict__ edst, const float4* __restrict__ A_s,
                      const float4* __restrict__ A_d, const float* __restrict__ W_att,
                      uint2* __restrict__ attb, int E) {
  __shared__ float4 s_we[32];                  // W_att[:,128:160]: 4 heads x 8 float4
  if (threadIdx.x < 32) {
    int h = threadIdx.x >> 3, k4 = threadIdx.x & 7;
    const float* p = &W_att[h * 160 + 128 + k4 * 4];
    s_we[threadIdx.x] = make_float4(p[0], p[1], p[2], p[3]);
  }
  __syncthreads();
  for (int e = blockIdx.x * blockDim.x + threadIdx.x; e < E; e += gridDim.x * blockDim.x) {
    const float4* ep = (const float4*)&ea[e * 32];
    float4 eq[8];
    #pragma unroll
    for (int k = 0; k < 8; k++) eq[k] = ep[k];
    int s = esrc[e], d = edst[e];
    float4 as4 = A_s[s], ad4 = A_d[d];
    float base[4] = {as4.x + ad4.x, as4.y + ad4.y, as4.z + ad4.z, as4.w + ad4.w};
    float av[4];
    #pragma unroll
    for (int h = 0; h < 4; h++) {
      float lg = base[h];
      #pragma unroll
      for (int k = 0; k < 8; k++) lg += dot4(s_we[h * 8 + k], eq[k]);
      lg = (lg > 0.f) ? lg : 0.2f * lg;
      av[h] = __expf(lg);
    }
    attb[e] = make_uint2(pk2(av[0], av[1]), pk2(av[2], av[3]));
  }
}

// ---------------- wave-per-node weighted aggregation ----------------
__launch_bounds__(256)
__global__ void k_agg(const float* __restrict__ x, const float* __restrict__ ea,
                      const uint2* __restrict__ attb, const int2* __restrict__ csr2,
                      const int* __restrict__ offsets, const int* __restrict__ deg,
                      unsigned short* __restrict__ agg, float* __restrict__ denom, int N) {
  const int lane = threadIdx.x & 63;
  const int wv = (blockIdx.x * blockDim.x + threadIdx.x) >> 6;
  const int nw = (gridDim.x * blockDim.x) >> 6;
  const int l8 = lane & 7;
  const int l32 = lane & 31;
  const bool hi = (lane & 32) != 0;

  for (int v = wv; v < N; v += nw) {
    const int start = offsets[v];
    const int dg = deg[v];
    float ax0 = 0, ax1 = 0, ax2 = 0, ax3 = 0, ae0 = 0, ae1 = 0;
    float ss0 = 0, ss1 = 0, ss2 = 0, ss3 = 0;

    if (dg > 0) {
      const int ng = (dg + 7) >> 3;
      int2 mid = csr2[start + min(l8, dg - 1)];         // ids for chunk 0
      for (int g = 0; g < ng; g++) {
        int2 cur = mid;
        if (g + 1 < ng)                                  // prefetch next chunk's ids
          mid = csr2[start + min((g + 1) * 8 + l8, dg - 1)];
        int sp[8], ep[8];
        #pragma unroll
        for (int p = 0; p < 8; p++) { sp[p] = __shfl(cur.x, p); ep[p] = __shfl(cur.y, p); }
        float xv[8], ev[8]; uint2 at[8];
        #pragma unroll
        for (int p = 0; p < 8; p++) xv[p] = x[sp[p] * 64 + lane];
        #pragma unroll
        for (int p = 0; p < 8; p++) ev[p] = ea[ep[p] * 32 + l32];
        #pragma unroll
        for (int p = 0; p < 8; p++) at[p] = attb[ep[p]];
        const int rem = dg - g * 8;
        #pragma unroll
        for (int p = 0; p < 8; p++) {
          const float msk = (p < rem) ? 1.f : 0.f;
          const float a0 = ubf(at[p].x & 0xffffu) * msk;
          const float a1 = ubf(at[p].x >> 16) * msk;
          const float a2 = ubf(at[p].y & 0xffffu) * msk;
          const float a3 = ubf(at[p].y >> 16) * msk;
          ax0 = fmaf(a0, xv[p], ax0);
          ax1 = fmaf(a1, xv[p], ax1);
          ax2 = fmaf(a2, xv[p], ax2);
          ax3 = fmaf(a3, xv[p], ax3);
          ae0 = fmaf(hi ? a2 : a0, ev[p], ae0);
          ae1 = fmaf(hi ? a3 : a1, ev[p], ae1);
          ss0 += a0; ss1 += a1; ss2 += a2; ss3 += a3;
        }
      }
    }
    const int base = v * 384;
    agg[base + lane]       = fbf(ax0);
    agg[base + 96 + lane]  = fbf(ax1);
    agg[base + 192 + lane] = fbf(ax2);
    agg[base + 288 + lane] = fbf(ax3);
    const int hA = hi ? 2 : 0;
    agg[base + hA * 96 + 64 + l32]       = fbf(ae0);
    agg[base + (hA + 1) * 96 + 64 + l32] = fbf(ae1);
    if (lane == 0) ((float4*)denom)[v] = make_float4(ss0, ss1, ss2, ss3);
  }
}

// ---------------- out = blockdiag(W_msg) * agg, /denom, +bias, LN ----------------
__launch_bounds__(128)
__global__ void k_out(const unsigned short* __restrict__ agg, const float* __restrict__ W_msg,
                      const float* __restrict__ denom, const float* __restrict__ bias,
                      const float* __restrict__ gamma, const float* __restrict__ beta,
                      float* __restrict__ out, int N, int T) {
  __shared__ float s_den[64];
  __shared__ float s_sum[2][16], s_sq[2][16];
  const int f = threadIdx.x;
  const int w = f >> 6;            // wave: heads 2w, 2w+1 -> cols 64w..64w+63
  const int l = f & 63;
  const int c16 = l & 15;
  const int rg = l >> 4;

  short8 wb[2][2][3];
  float biasv[2][2], gv[2][2], bv[2][2];
  #pragma unroll
  for (int hh = 0; hh < 2; hh++) {
    const int head = 2 * w + hh;
    #pragma unroll
    for (int ct = 0; ct < 2; ct++) {
      const int q = head * 32 + ct * 16 + c16;
      biasv[hh][ct] = bias[q]; gv[hh][ct] = gamma[q]; bv[hh][ct] = beta[q];
      #pragma unroll
      for (int kk = 0; kk < 3; kk++) {
        const float* p = &W_msg[q * 96 + kk * 32 + rg * 8];
        short8 s;
        #pragma unroll
        for (int i = 0; i < 8; i++) s[i] = (short)fbf(p[i]);
        wb[hh][ct][kk] = s;
      }
    }
  }

  for (int t = blockIdx.x; t < T; t += gridDim.x) {
    const int n0 = t * 16;
    if (f < 64) s_den[f] = denom[min(n0 + (f >> 2), N - 1) * 4 + (f & 3)];
    __syncthreads();

    f32x4 c[2][2] = {{{0.f,0.f,0.f,0.f},{0.f,0.f,0.f,0.f}},
                     {{0.f,0.f,0.f,0.f},{0.f,0.f,0.f,0.f}}};
    const int nA = min(n0 + c16, N - 1);
    #pragma unroll
    for (int hh = 0; hh < 2; hh++) {
      const int head = 2 * w + hh;
      #pragma unroll
      for (int kk = 0; kk < 3; kk++) {
        short8 a = *(const short8*)&agg[nA * 384 + head * 96 + kk * 32 + rg * 8];
        c[hh][0] = __builtin_amdgcn_mfma_f32_16x16x32_bf16(a, wb[hh][0][kk], c[hh][0], 0, 0, 0);
        c[hh][1] = __builtin_amdgcn_mfma_f32_16x16x32_bf16(a, wb[hh][1][kk], c[hh][1], 0, 0, 0);
      }
    }

    // normalize + bias
    float val[2][2][4];
    #pragma unroll
    for (int hh = 0; hh < 2; hh++)
      #pragma unroll
      for (int ct = 0; ct < 2; ct++)
        #pragma unroll
        for (int r = 0; r < 4; r++) {
          const float d = s_den[(rg * 4 + r) * 4 + (2 * w + hh)] + 1e-9f;
          val[hh][ct][r] = c[hh][ct][r] / d + biasv[hh][ct];
        }

    // LN partials over this wave's 64 cols
    float sr[4], qr[4];
    #pragma unroll
    for (int r = 0; r < 4; r++) {
      float s = 0.f, q2 = 0.f;
      #pragma unroll
      for (int hh = 0; hh < 2; hh++)
        #pragma unroll
        for (int ct = 0; ct < 2; ct++) { s += val[hh][ct][r]; q2 = fmaf(val[hh][ct][r], val[hh][ct][r], q2); }
      #pragma unroll
      for (int m = 1; m <= 8; m <<= 1) { s += __shfl_xor(s, m, 64); q2 += __shfl_xor(q2, m, 64); }
      sr[r] = s; qr[r] = q2;
    }
    if (c16 == 0) {
      #pragma unroll
      for (int r = 0; r < 4; r++) { s_sum[w][rg * 4 + r] = sr[r]; s_sq[w][rg * 4 + r] = qr[r]; }
    }
    __syncthreads();

    float mean[4], rstd[4];
    #pragma unroll
    for (int r = 0; r < 4; r++) {
      const int ni = rg * 4 + r;
      mean[r] = (s_sum[0][ni] + s_sum[1][ni]) * (1.f / 128.f);
      const float m2 = (s_sq[0][ni] + s_sq[1][ni]) * (1.f / 128.f);
      rstd[r] = rsqrtf(m2 - mean[r] * mean[r] + 1e-5f);
    }
    #pragma unroll
    for (int hh = 0; hh < 2; hh++)
      #pragma unroll
      for (int ct = 0; ct < 2; ct++)
        #pragma unroll
        for (int r = 0; r < 4; r++) {
          const int n = n0 + rg * 4 + r;
          if (n < N)
            out[n * 128 + (2 * w + hh) * 32 + ct * 16 + c16] =
                (val[hh][ct][r] - mean[r]) * rstd[r] * gv[hh][ct] + bv[hh][ct];
        }
    __syncthreads();
  }
}

extern "C" void kernel_launch(void* const* d_in, const int* in_sizes, int n_in,
                              void* d_out, int out_size, void* d_ws, size_t ws_size,
                              hipStream_t stream) {
  const float* x     = (const float*)d_in[0];
  const int*   ei    = (const int*)d_in[1];
  const float* ea    = (const float*)d_in[2];
  const float* W_msg = (const float*)d_in[3];
  const float* W_att = (const float*)d_in[4];
  const float* bias  = (const float*)d_in[5];
  const float* gamma = (const float*)d_in[6];
  const float* beta  = (const float*)d_in[7];
  float* out = (float*)d_out;

  const int N = in_sizes[0] / 64;
  const int E = in_sizes[1] / 2;
  const int* esrc = ei;
  const int* edst = ei + E;

  char* p = (char*)d_ws;
  int* deg      = (int*)p;            p += (size_t)N * 4;
  int* offsets  = (int*)p;            p += (size_t)N * 4;
  int* cursor   = (int*)p;            p += (size_t)N * 4;
  int* bsum     = (int*)p;            p += 2048 * 4;
  int2* csr2    = (int2*)p;           p += (size_t)E * 8;
  float4* A_s   = (float4*)p;         p += (size_t)N * 16;
  float4* A_d   = (float4*)p;         p += (size_t)N * 16;
  uint2* attb   = (uint2*)p;          p += (size_t)E * 8;
  unsigned short* agg = (unsigned short*)p; p += (size_t)N * 384 * 2;
  float* denom  = (float*)p;

  hipMemsetAsync(deg, 0, (size_t)N * sizeof(int), stream);
  const int SB = (N + 1023) / 1024;
  const int T = (N + 15) / 16;

  k_count<<<2048, 256, 0, stream>>>(edst, E, deg);
  k_scan1<<<SB, 1024, 0, stream>>>(deg, N, offsets, bsum);
  k_scan2<<<SB, 1024, 0, stream>>>(offsets, bsum, N, cursor);
  k_fill<<<2048, 256, 0, stream>>>(esrc, edst, E, cursor, csr2);
  k_pre<<<(N + 255) / 256, 256, 0, stream>>>(x, W_att, A_s, A_d, N);
  k_att<<<2048, 256, 0, stream>>>(ea, esrc, edst, A_s, A_d, W_att, attb, E);
  k_agg<<<2048, 256, 0, stream>>>(x, ea, attb, csr2, offsets, deg, agg, denom, N);
  k_out<<<2048, 128, 0, stream>>>(agg, W_msg, denom, bias, gamma, beta, out, N, T);
}

// Round 5
// 413.941 us; speedup vs baseline: 4.4129x; 1.2519x over previous
//
#include <hip/hip_runtime.h>
#include <hip/hip_bf16.h>

typedef __attribute__((ext_vector_type(8))) short short8;
typedef __attribute__((ext_vector_type(4))) float f32x4;

__device__ __forceinline__ unsigned short fbf(float f) {
  union { float f; unsigned u; } v; v.f = f;
  unsigned r = v.u + 0x7fffu + ((v.u >> 16) & 1u);   // RNE
  return (unsigned short)(r >> 16);
}
__device__ __forceinline__ unsigned pk2(float a, float b) {
  return (unsigned)fbf(a) | ((unsigned)fbf(b) << 16);
}
__device__ __forceinline__ float ubf(unsigned hi) {   // bf16 bits (low16) -> float
  union { unsigned u; float f; } v; v.u = hi << 16; return v.f;
}
__device__ __forceinline__ float dot4(float4 a, float4 b) {
  return fmaf(a.x, b.x, fmaf(a.y, b.y, fmaf(a.z, b.z, a.w * b.w)));
}

// ---------------- CSR build ----------------
__global__ void k_count(const int* __restrict__ dst, int E, int* __restrict__ deg) {
  for (int i = blockIdx.x * blockDim.x + threadIdx.x; i < E; i += gridDim.x * blockDim.x)
    atomicAdd(&deg[dst[i]], 1);
}

__global__ void k_scan1(const int* __restrict__ deg, int N, int* __restrict__ part,
                        int* __restrict__ bsum) {
  __shared__ int tmp[1024];
  int tid = threadIdx.x;
  int i = blockIdx.x * 1024 + tid;
  int v = (i < N) ? deg[i] : 0;
  tmp[tid] = v;
  __syncthreads();
  for (int ofs = 1; ofs < 1024; ofs <<= 1) {
    int t = (tid >= ofs) ? tmp[tid - ofs] : 0;
    __syncthreads();
    tmp[tid] += t;
    __syncthreads();
  }
  if (i < N) part[i] = tmp[tid] - v;
  if (tid == 1023) bsum[blockIdx.x] = tmp[tid];
}

__global__ void k_scan2(int* __restrict__ part, const int* __restrict__ bsum, int N,
                        int* __restrict__ cursor) {
  __shared__ int sbase;
  if (threadIdx.x == 0) {
    int b = 0;
    for (int j = 0; j < (int)blockIdx.x; j++) b += bsum[j];
    sbase = b;
  }
  __syncthreads();
  int i = blockIdx.x * 1024 + threadIdx.x;
  if (i < N) {
    int o = part[i] + sbase;
    part[i] = o;
    cursor[i] = o;
  }
}

__global__ void k_fill(const int* __restrict__ src, const int* __restrict__ dst, int E,
                       int* __restrict__ cursor, int2* __restrict__ csr2) {
  for (int i = blockIdx.x * blockDim.x + threadIdx.x; i < E; i += gridDim.x * blockDim.x) {
    int d = dst[i];
    int slot = atomicAdd(&cursor[d], 1);
    csr2[slot] = make_int2(src[i], i);
  }
}

// ---------------- A_s / A_d tables ----------------
__launch_bounds__(256)
__global__ void k_pre(const float* __restrict__ x, const float* __restrict__ W_att,
                      float4* __restrict__ A_s, float4* __restrict__ A_d, int N) {
  __shared__ float4 s_wa[160];                 // 4 heads x 40 float4 (row len 160)
  if (threadIdx.x < 160) s_wa[threadIdx.x] = ((const float4*)W_att)[threadIdx.x];
  __syncthreads();
  for (int v = blockIdx.x * blockDim.x + threadIdx.x; v < N; v += gridDim.x * blockDim.x) {
    const float4* xp = (const float4*)&x[v * 64];
    float4 xq[16];
    #pragma unroll
    for (int k = 0; k < 16; k++) xq[k] = xp[k];
    float as[4] = {}, ad[4] = {};
    #pragma unroll
    for (int h = 0; h < 4; h++) {
      #pragma unroll
      for (int k = 0; k < 16; k++) {
        as[h] += dot4(s_wa[h * 40 + k], xq[k]);
        ad[h] += dot4(s_wa[h * 40 + 16 + k], xq[k]);
      }
    }
    A_s[v] = make_float4(as[0], as[1], as[2], as[3]);
    A_d[v] = make_float4(ad[0], ad[1], ad[2], ad[3]);
  }
}

// ---------------- x -> bf16 copy ----------------
__launch_bounds__(256)
__global__ void k_cvt(const float* __restrict__ x, unsigned* __restrict__ xb2, int n4) {
  for (int i = blockIdx.x * blockDim.x + threadIdx.x; i < n4; i += gridDim.x * blockDim.x) {
    float4 t = ((const float4*)x)[i];
    xb2[i * 2]     = pk2(t.x, t.y);
    xb2[i * 2 + 1] = pk2(t.z, t.w);
  }
}

// ---------------- fused att + weighted aggregation (wave per node) ----------------
__launch_bounds__(256)
__global__ void k_agg(const unsigned short* __restrict__ xb, const float* __restrict__ ea,
                      const float4* __restrict__ A_s, const float4* __restrict__ A_d,
                      const float* __restrict__ W_att,
                      const int2* __restrict__ csr2, const int* __restrict__ offsets,
                      const int* __restrict__ deg,
                      unsigned short* __restrict__ agg, float* __restrict__ denom, int N) {
  __shared__ int2 s_ids[4][8];       // wave-local, no barriers needed
  __shared__ float4 s_att[4][8];
  const int lane = threadIdx.x & 63;
  const int wvb = threadIdx.x >> 6;
  const int wv = (blockIdx.x * blockDim.x + threadIdx.x) >> 6;
  const int nw = (gridDim.x * blockDim.x) >> 6;
  const int l8 = lane & 7;
  const int l32 = lane & 31;
  const bool hi = (lane & 32) != 0;
  const int pj = lane >> 3;          // this lane's logit edge (0..7)
  const int jc = lane & 7;           // this lane's float4 chunk of ea row

  float4 wea[4];
  #pragma unroll
  for (int h = 0; h < 4; h++)
    wea[h] = *(const float4*)&W_att[h * 160 + 128 + jc * 4];

  for (int v = wv; v < N; v += nw) {
    const int start = offsets[v];
    const int dg = deg[v];
    const float4 adv = A_d[v];
    float ax0 = 0, ax1 = 0, ax2 = 0, ax3 = 0, ae0 = 0, ae1 = 0;
    float ss0 = 0, ss1 = 0, ss2 = 0, ss3 = 0;

    if (dg > 0) {
      const int ng = (dg + 7) >> 3;
      int2 cur = csr2[start + min(l8, dg - 1)];
      for (int g = 0; g < ng; g++) {
        if (lane < 8) s_ids[wvb][lane] = cur;
        if (g + 1 < ng)
          cur = csr2[start + min((g + 1) * 8 + l8, dg - 1)];
        int2 idl = s_ids[wvb][pj];               // broadcast read (same wave)
        float4 ef = *(const float4*)&ea[(size_t)idl.y * 32 + jc * 4];
        float4 asv = A_s[idl.x];
        int sp[8], ep[8];
        #pragma unroll
        for (int p = 0; p < 8; p++) { int2 t = s_ids[wvb][p]; sp[p] = t.x; ep[p] = t.y; }
        float xv[8], ev[8];
        #pragma unroll
        for (int p = 0; p < 8; p++) xv[p] = ubf(xb[(size_t)sp[p] * 64 + lane]);
        #pragma unroll
        for (int p = 0; p < 8; p++) ev[p] = ea[(size_t)ep[p] * 32 + l32];
        // logits: 4 head-dots over this lane's 4 ea elems, reduced over 8 lanes
        float lp0 = dot4(wea[0], ef), lp1 = dot4(wea[1], ef);
        float lp2 = dot4(wea[2], ef), lp3 = dot4(wea[3], ef);
        #pragma unroll
        for (int m = 1; m <= 4; m <<= 1) {
          lp0 += __shfl_xor(lp0, m, 64);
          lp1 += __shfl_xor(lp1, m, 64);
          lp2 += __shfl_xor(lp2, m, 64);
          lp3 += __shfl_xor(lp3, m, 64);
        }
        const float msk = (g * 8 + pj < dg) ? 1.f : 0.f;
        float4 av; float lg;
        lg = lp0 + asv.x + adv.x; lg = (lg > 0.f) ? lg : 0.2f * lg; av.x = msk * __expf(lg);
        lg = lp1 + asv.y + adv.y; lg = (lg > 0.f) ? lg : 0.2f * lg; av.y = msk * __expf(lg);
        lg = lp2 + asv.z + adv.z; lg = (lg > 0.f) ? lg : 0.2f * lg; av.z = msk * __expf(lg);
        lg = lp3 + asv.w + adv.w; lg = (lg > 0.f) ? lg : 0.2f * lg; av.w = msk * __expf(lg);
        if (jc == 0) s_att[wvb][pj] = av;
        #pragma unroll
        for (int p = 0; p < 8; p++) {
          float4 ap = s_att[wvb][p];             // uniform b128 broadcast
          ax0 = fmaf(ap.x, xv[p], ax0);
          ax1 = fmaf(ap.y, xv[p], ax1);
          ax2 = fmaf(ap.z, xv[p], ax2);
          ax3 = fmaf(ap.w, xv[p], ax3);
          ae0 = fmaf(hi ? ap.z : ap.x, ev[p], ae0);
          ae1 = fmaf(hi ? ap.w : ap.y, ev[p], ae1);
          ss0 += ap.x; ss1 += ap.y; ss2 += ap.z; ss3 += ap.w;
        }
      }
    }
    const int base = v * 384;
    agg[base + lane]       = fbf(ax0);
    agg[base + 96 + lane]  = fbf(ax1);
    agg[base + 192 + lane] = fbf(ax2);
    agg[base + 288 + lane] = fbf(ax3);
    const int hA = hi ? 2 : 0;
    agg[base + hA * 96 + 64 + l32]       = fbf(ae0);
    agg[base + (hA + 1) * 96 + 64 + l32] = fbf(ae1);
    if (lane == 0) ((float4*)denom)[v] = make_float4(ss0, ss1, ss2, ss3);
  }
}

// ---------------- out = blockdiag(W_msg) * agg, /denom, +bias, LN ----------------
__launch_bounds__(128)
__global__ void k_out(const unsigned short* __restrict__ agg, const float* __restrict__ W_msg,
                      const float* __restrict__ denom, const float* __restrict__ bias,
                      const float* __restrict__ gamma, const float* __restrict__ beta,
                      float* __restrict__ out, int N, int T) {
  __shared__ float s_den[64];
  __shared__ float s_sum[2][16], s_sq[2][16];
  const int f = threadIdx.x;
  const int w = f >> 6;            // wave: heads 2w, 2w+1 -> cols 64w..64w+63
  const int l = f & 63;
  const int c16 = l & 15;
  const int rg = l >> 4;

  short8 wb[2][2][3];
  float biasv[2][2], gv[2][2], bv[2][2];
  #pragma unroll
  for (int hh = 0; hh < 2; hh++) {
    const int head = 2 * w + hh;
    #pragma unroll
    for (int ct = 0; ct < 2; ct++) {
      const int q = head * 32 + ct * 16 + c16;
      biasv[hh][ct] = bias[q]; gv[hh][ct] = gamma[q]; bv[hh][ct] = beta[q];
      #pragma unroll
      for (int kk = 0; kk < 3; kk++) {
        const float* p = &W_msg[q * 96 + kk * 32 + rg * 8];
        short8 s;
        #pragma unroll
        for (int i = 0; i < 8; i++) s[i] = (short)fbf(p[i]);
        wb[hh][ct][kk] = s;
      }
    }
  }

  for (int t = blockIdx.x; t < T; t += gridDim.x) {
    const int n0 = t * 16;
    if (f < 64) s_den[f] = denom[min(n0 + (f >> 2), N - 1) * 4 + (f & 3)];
    __syncthreads();

    f32x4 c[2][2] = {{{0.f,0.f,0.f,0.f},{0.f,0.f,0.f,0.f}},
                     {{0.f,0.f,0.f,0.f},{0.f,0.f,0.f,0.f}}};
    const int nA = min(n0 + c16, N - 1);
    #pragma unroll
    for (int hh = 0; hh < 2; hh++) {
      const int head = 2 * w + hh;
      #pragma unroll
      for (int kk = 0; kk < 3; kk++) {
        short8 a = *(const short8*)&agg[nA * 384 + head * 96 + kk * 32 + rg * 8];
        c[hh][0] = __builtin_amdgcn_mfma_f32_16x16x32_bf16(a, wb[hh][0][kk], c[hh][0], 0, 0, 0);
        c[hh][1] = __builtin_amdgcn_mfma_f32_16x16x32_bf16(a, wb[hh][1][kk], c[hh][1], 0, 0, 0);
      }
    }

    float val[2][2][4];
    #pragma unroll
    for (int hh = 0; hh < 2; hh++)
      #pragma unroll
      for (int ct = 0; ct < 2; ct++)
        #pragma unroll
        for (int r = 0; r < 4; r++) {
          const float d = s_den[(rg * 4 + r) * 4 + (2 * w + hh)] + 1e-9f;
          val[hh][ct][r] = c[hh][ct][r] / d + biasv[hh][ct];
        }

    float sr[4], qr[4];
    #pragma unroll
    for (int r = 0; r < 4; r++) {
      float s = 0.f, q2 = 0.f;
      #pragma unroll
      for (int hh = 0; hh < 2; hh++)
        #pragma unroll
        for (int ct = 0; ct < 2; ct++) { s += val[hh][ct][r]; q2 = fmaf(val[hh][ct][r], val[hh][ct][r], q2); }
      #pragma unroll
      for (int m = 1; m <= 8; m <<= 1) { s += __shfl_xor(s, m, 64); q2 += __shfl_xor(q2, m, 64); }
      sr[r] = s; qr[r] = q2;
    }
    if (c16 == 0) {
      #pragma unroll
      for (int r = 0; r < 4; r++) { s_sum[w][rg * 4 + r] = sr[r]; s_sq[w][rg * 4 + r] = qr[r]; }
    }
    __syncthreads();

    float mean[4], rstd[4];
    #pragma unroll
    for (int r = 0; r < 4; r++) {
      const int ni = rg * 4 + r;
      mean[r] = (s_sum[0][ni] + s_sum[1][ni]) * (1.f / 128.f);
      const float m2 = (s_sq[0][ni] + s_sq[1][ni]) * (1.f / 128.f);
      rstd[r] = rsqrtf(m2 - mean[r] * mean[r] + 1e-5f);
    }
    #pragma unroll
    for (int hh = 0; hh < 2; hh++)
      #pragma unroll
      for (int ct = 0; ct < 2; ct++)
        #pragma unroll
        for (int r = 0; r < 4; r++) {
          const int n = n0 + rg * 4 + r;
          if (n < N)
            out[n * 128 + (2 * w + hh) * 32 + ct * 16 + c16] =
                (val[hh][ct][r] - mean[r]) * rstd[r] * gv[hh][ct] + bv[hh][ct];
        }
    __syncthreads();
  }
}

extern "C" void kernel_launch(void* const* d_in, const int* in_sizes, int n_in,
                              void* d_out, int out_size, void* d_ws, size_t ws_size,
                              hipStream_t stream) {
  const float* x     = (const float*)d_in[0];
  const int*   ei    = (const int*)d_in[1];
  const float* ea    = (const float*)d_in[2];
  const float* W_msg = (const float*)d_in[3];
  const float* W_att = (const float*)d_in[4];
  const float* bias  = (const float*)d_in[5];
  const float* gamma = (const float*)d_in[6];
  const float* beta  = (const float*)d_in[7];
  float* out = (float*)d_out;

  const int N = in_sizes[0] / 64;
  const int E = in_sizes[1] / 2;
  const int* esrc = ei;
  const int* edst = ei + E;

  char* p = (char*)d_ws;
  int* deg      = (int*)p;            p += (size_t)N * 4;
  int* offsets  = (int*)p;            p += (size_t)N * 4;
  int* cursor   = (int*)p;            p += (size_t)N * 4;
  int* bsum     = (int*)p;            p += 2048 * 4;
  int2* csr2    = (int2*)p;           p += (size_t)E * 8;
  float4* A_s   = (float4*)p;         p += (size_t)N * 16;
  float4* A_d   = (float4*)p;         p += (size_t)N * 16;
  unsigned short* xb = (unsigned short*)p; p += (size_t)N * 64 * 2;
  unsigned short* agg = (unsigned short*)p; p += (size_t)N * 384 * 2;
  float* denom  = (float*)p;

  hipMemsetAsync(deg, 0, (size_t)N * sizeof(int), stream);
  const int SB = (N + 1023) / 1024;
  const int T = (N + 15) / 16;

  k_count<<<2048, 256, 0, stream>>>(edst, E, deg);
  k_scan1<<<SB, 1024, 0, stream>>>(deg, N, offsets, bsum);
  k_scan2<<<SB, 1024, 0, stream>>>(offsets, bsum, N, cursor);
  k_fill<<<2048, 256, 0, stream>>>(esrc, edst, E, cursor, csr2);
  k_pre<<<(N + 255) / 256, 256, 0, stream>>>(x, W_att, A_s, A_d, N);
  k_cvt<<<2048, 256, 0, stream>>>(x, (unsigned*)xb, N * 16);
  k_agg<<<2048, 256, 0, stream>>>(xb, ea, A_s, A_d, W_att, csr2, offsets, deg,
                                  agg, denom, N);
  k_out<<<2048, 128, 0, stream>>>(agg, W_msg, denom, bias, gamma, beta, out, N, T);
}